// Round 2
// baseline (204.089 us; speedup 1.0000x reference)
//
#include <hip/hip_runtime.h>

#define INF_DELTA 1e10f
#define LOG2E 1.4426950408889634f
#define LOG2_EPS -33.219280948873623f   // log2(1e-10)
#define RPW 4                           // rays per wave

// DPP helper: returns src permuted by CTRL; lanes not written (row_mask) or
// reading out-of-bounds produce 0 (old=0) — the additive identity.
template<int CTRL, int RMASK>
__device__ __forceinline__ float dpp0(float v) {
    return __int_as_float(
        __builtin_amdgcn_update_dpp(0, __float_as_int(v), CTRL, RMASK, 0xF, false));
}

// Canonical gfx9 wave64 inclusive add-scan: 6 full-rate DPP ops, no LDS pipe.
__device__ __forceinline__ float wave_incl_scan_add(float v) {
    v += dpp0<0x111, 0xF>(v);  // row_shr:1
    v += dpp0<0x112, 0xF>(v);  // row_shr:2
    v += dpp0<0x114, 0xF>(v);  // row_shr:4
    v += dpp0<0x118, 0xF>(v);  // row_shr:8
    v += dpp0<0x142, 0xA>(v);  // row_bcast:15 -> rows 1,3
    v += dpp0<0x143, 0xC>(v);  // row_bcast:31 -> rows 2,3
    return v;
}

// One 64-lane wave per 4 rays; lane s owns sample s of each ray.
// All ~16 loads issue before any use -> 4x memory-level parallelism per wave.
__global__ __launch_bounds__(256) void raymarch_kernel(
    const float* __restrict__ colors,      // (n_rays, 64, 3)
    const float* __restrict__ densities,   // (n_rays, 64)
    const float* __restrict__ depths,      // (n_rays, 64)
    float* __restrict__ rgb_out,           // (n_rays, 3)
    float* __restrict__ depth_out,         // (n_rays,)
    float* __restrict__ weights_out,       // (n_rays, 64)
    float* __restrict__ trans_out,         // (n_rays,)
    int n_rays)
{
    const int lane = threadIdx.x & 63;
    const int wid  = threadIdx.x >> 6;
    const int ray0 = (blockIdx.x * 4 + wid) * RPW;
    if (ray0 >= n_rays) return;

    int rayk[RPW];
    #pragma unroll
    for (int k = 0; k < RPW; ++k)
        rayk[k] = (ray0 + k < n_rays) ? (ray0 + k) : (n_rays - 1);

    // ---- Load phase: everything in flight at once ----
    float d[RPW], dn[RPW], x[RPW], c0[RPW], c1[RPW], c2[RPW];
    #pragma unroll
    for (int k = 0; k < RPW; ++k) {
        const long b = (long)rayk[k] * 64 + lane;
        d[k]  = depths[b];
        dn[k] = depths[b + ((lane < 63) ? 1 : 0)];   // L1-hit overlapping load
        x[k]  = densities[b];
        const float* cp = colors + (long)rayk[k] * 192 + lane * 3;
        c0[k] = cp[0]; c1[k] = cp[1]; c2[k] = cp[2];
    }

    // ---- Compute phase: 4 independent chains, scheduler interleaves ----
    float S[RPW], w[RPW], finalT[RPW];
    #pragma unroll
    for (int k = 0; k < RPW; ++k) {
        const float delta = (lane == 63) ? INF_DELTA : (dn[k] - d[k]);

        // log2-domain softplus: log2(1+e^x) = relu(x)*log2e + log2(1+exp2(-|x|*log2e))
        const float q   = __builtin_amdgcn_exp2f(-__builtin_fabsf(x[k]) * LOG2E);
        const float l2  = __builtin_amdgcn_logf(1.0f + q);
        const float sp2 = __builtin_fmaf(__builtin_fmaxf(x[k], 0.0f), LOG2E, l2);
        const float g   = -delta * sp2;                  // log2(y)
        const float y   = __builtin_amdgcn_exp2f(g);
        const float alpha = 1.0f - y;

        // log2(y + 1e-10) ~= max(g, log2(1e-10)); error confined to trans <= 2e-10.
        const float llane = __builtin_fmaxf(g, LOG2_EPS);

        S[k] = wave_incl_scan_add(llane);                // inclusive cumsum of log2
        const float trans_excl = __builtin_amdgcn_exp2f(S[k] - llane);
        w[k] = alpha * trans_excl;
        finalT[k] = __builtin_amdgcn_exp2f(S[k]);        // only lane 63's value used
    }

    // ---- Weights: 4 coalesced 256B stores ----
    #pragma unroll
    for (int k = 0; k < RPW; ++k)
        weights_out[(long)rayk[k] * 64 + lane] = w[k];

    // ---- Reductions: 4 independent chains ----
    float v[RPW];
    #pragma unroll
    for (int k = 0; k < RPW; ++k) {
        float s0 = w[k] * c0[k], s1 = w[k] * c1[k], s2 = w[k] * c2[k], s3 = w[k] * d[k];
        s0 += dpp0<0xB1, 0xF>(s0);  // quad_perm [1,0,3,2]
        s1 += dpp0<0xB1, 0xF>(s1);
        s2 += dpp0<0xB1, 0xF>(s2);
        s3 += dpp0<0xB1, 0xF>(s3);
        s0 += dpp0<0x4E, 0xF>(s0);  // quad_perm [2,3,0,1]
        s1 += dpp0<0x4E, 0xF>(s1);
        s2 += dpp0<0x4E, 0xF>(s2);
        s3 += dpp0<0x4E, 0xF>(s3);

        const int sel = lane & 3;
        float t = (sel == 0) ? s0 : (sel == 1) ? s1 : (sel == 2) ? s2 : s3;
        t += dpp0<0x124, 0xF>(t);   // row_ror:4
        t += dpp0<0x128, 0xF>(t);   // row_ror:8
        t += __int_as_float(__builtin_amdgcn_ds_swizzle(__float_as_int(t), 0x401F)); // xor16
        t += __shfl_xor(t, 32, 64); // cross-half
        v[k] = t;
    }

    // ---- Scalars / rgb ----
    #pragma unroll
    for (int k = 0; k < RPW; ++k) {
        if (ray0 + k >= n_rays) break;
        if (lane < 3) {
            rgb_out[(long)rayk[k] * 3 + lane] = v[k];
        } else if (lane == 3) {
            depth_out[rayk[k]] = v[k];
        } else if (lane == 63) {
            trans_out[rayk[k]] = finalT[k];
        }
    }
}

extern "C" void kernel_launch(void* const* d_in, const int* in_sizes, int n_in,
                              void* d_out, int out_size, void* d_ws, size_t ws_size,
                              hipStream_t stream) {
    const float* colors    = (const float*)d_in[0];
    const float* densities = (const float*)d_in[1];
    const float* depths    = (const float*)d_in[2];

    const int n_rays = in_sizes[1] / 64;   // densities flat count = n_rays * 64

    float* out      = (float*)d_out;
    float* rgb      = out;                              // n_rays*3
    float* depth_o  = rgb + (long)n_rays * 3;           // n_rays
    float* weights  = depth_o + n_rays;                 // n_rays*64
    float* trans    = weights + (long)n_rays * 64;      // n_rays

    const int rays_per_block = 4 * RPW;                 // 4 waves x RPW rays
    const int blocks = (n_rays + rays_per_block - 1) / rays_per_block;
    raymarch_kernel<<<blocks, 256, 0, stream>>>(
        colors, densities, depths, rgb, depth_o, weights, trans, n_rays);
}

// Round 3
// 201.348 us; speedup vs baseline: 1.0136x; 1.0136x over previous
//
#include <hip/hip_runtime.h>

#define INF_DELTA 1e10f
#define LOG2E 1.4426950408889634f
#define LOG2_EPS -33.219280948873623f   // log2(1e-10)

// DPP helper: old=0, bound_ctrl=false -> out-of-range reads produce 0
// (additive identity). Row ops are confined to 16-lane rows.
template<int CTRL, int RMASK>
__device__ __forceinline__ float dpp0(float v) {
    return __int_as_float(
        __builtin_amdgcn_update_dpp(0, __float_as_int(v), CTRL, RMASK, 0xF, false));
}

__device__ __forceinline__ float log2_softplus(float x) {
    // log2(1+e^x) = relu(x)*log2e + log2(1 + exp2(-|x|*log2e))
    const float q  = __builtin_amdgcn_exp2f(-__builtin_fabsf(x) * LOG2E);
    const float l2 = __builtin_amdgcn_logf(1.0f + q);
    return __builtin_fmaf(__builtin_fmaxf(x, 0.0f), LOG2E, l2);
}

// Wave64 owns 4 consecutive rays: 16-lane row per ray, lane owns 4 consecutive
// samples. Every global access is a 16B/lane dwordx4 (1024B per instruction):
//   depths 1 load, densities 1 load, colors 3 loads, weights 1 store.
// Lane-address count per ray drops ~4.5x vs the dword version.
__global__ __launch_bounds__(256) void raymarch_kernel(
    const float* __restrict__ colors,      // (n_rays, 64, 3)
    const float* __restrict__ densities,   // (n_rays, 64)
    const float* __restrict__ depths,      // (n_rays, 64)
    float* __restrict__ rgb_out,           // (n_rays, 3)
    float* __restrict__ depth_out,         // (n_rays,)
    float* __restrict__ weights_out,       // (n_rays, 64)
    float* __restrict__ trans_out,         // (n_rays,)
    int n_rays)
{
    const int lane = threadIdx.x & 63;
    const int wid  = threadIdx.x >> 6;
    const int blk  = blockIdx.x * 4 + wid;       // 4-ray block index
    const int nblk = n_rays >> 2;
    if (blk >= nblk) return;

    const long fbase = (long)blk * 256;          // first flat sample of block

    // ---- 5 x global_load_dwordx4, all in flight before first use ----
    const float4 d4 = *reinterpret_cast<const float4*>(depths    + fbase + lane * 4);
    const float4 x4 = *reinterpret_cast<const float4*>(densities + fbase + lane * 4);
    const float* cp = colors + fbase * 3 + lane * 12;   // 48B/lane, 16B aligned
    const float4 ca = *reinterpret_cast<const float4*>(cp);
    const float4 cb = *reinterpret_cast<const float4*>(cp + 4);
    const float4 cc = *reinterpret_cast<const float4*>(cp + 8);
    // lane's samples: s0..s3 ; colors: s0=(ca.x,ca.y,ca.z) s1=(ca.w,cb.x,cb.y)
    //                          s2=(cb.z,cb.w,cc.x) s3=(cc.y,cc.z,cc.w)

    // ---- deltas: seam value from next lane via DPP row_shl:1 ----
    const float dnx  = dpp0<0x101, 0xF>(d4.x);   // lane l <- lane l+1's s0
    const float del0 = d4.y - d4.x;
    const float del1 = d4.z - d4.y;
    const float del2 = d4.w - d4.z;
    const float del3 = ((lane & 15) == 15) ? INF_DELTA : (dnx - d4.w);

    // ---- per-sample log2-domain alpha ----
    const float g0 = -del0 * log2_softplus(x4.x);
    const float g1 = -del1 * log2_softplus(x4.y);
    const float g2 = -del2 * log2_softplus(x4.z);
    const float g3 = -del3 * log2_softplus(x4.w);
    const float a0 = 1.0f - __builtin_amdgcn_exp2f(g0);
    const float a1 = 1.0f - __builtin_amdgcn_exp2f(g1);
    const float a2 = 1.0f - __builtin_amdgcn_exp2f(g2);
    const float a3 = 1.0f - __builtin_amdgcn_exp2f(g3);
    // log2(y + 1e-10) ~= max(g, log2(1e-10))
    const float l0 = __builtin_fmaxf(g0, LOG2_EPS);
    const float l1 = __builtin_fmaxf(g1, LOG2_EPS);
    const float l2 = __builtin_fmaxf(g2, LOG2_EPS);
    const float l3 = __builtin_fmaxf(g3, LOG2_EPS);

    // ---- cumsum: serial-4 local + 4-step DPP scan across the 16-lane row ----
    const float L0 = l0;
    const float L1 = L0 + l1;
    const float L2 = L1 + l2;
    const float L3 = L2 + l3;
    float p = L3;
    p += dpp0<0x111, 0xF>(p);   // row_shr:1
    p += dpp0<0x112, 0xF>(p);   // row_shr:2
    p += dpp0<0x114, 0xF>(p);   // row_shr:4
    p += dpp0<0x118, 0xF>(p);   // row_shr:8  (row-confined: full 16-lane scan)
    const float excl = p - L3;  // exclusive lane prefix

    // trans_excl per sample = exp2(excl + L_{j-1})
    const float e0 = __builtin_amdgcn_exp2f(excl);
    const float e1 = __builtin_amdgcn_exp2f(excl + L0);
    const float e2 = __builtin_amdgcn_exp2f(excl + L1);
    const float e3 = __builtin_amdgcn_exp2f(excl + L2);

    const float w0 = a0 * e0;
    const float w1 = a1 * e1;
    const float w2 = a2 * e2;
    const float w3 = a3 * e3;

    // ---- weights: one dwordx4 store (1024B coalesced per wave) ----
    float4 wv; wv.x = w0; wv.y = w1; wv.z = w2; wv.w = w3;
    *reinterpret_cast<float4*>(weights_out + fbase + lane * 4) = wv;

    // ---- per-ray reductions (r,g,b,depth) within each 16-lane row ----
    float p0 = w0 * ca.x + w1 * ca.w + w2 * cb.z + w3 * cc.y;   // R
    float p1 = w0 * ca.y + w1 * cb.x + w2 * cb.w + w3 * cc.z;   // G
    float p2 = w0 * ca.z + w1 * cb.y + w2 * cc.x + w3 * cc.w;   // B
    float p3 = w0 * d4.x + w1 * d4.y + w2 * d4.z + w3 * d4.w;   // depth

    p0 += dpp0<0xB1, 0xF>(p0);  // quad_perm [1,0,3,2]
    p1 += dpp0<0xB1, 0xF>(p1);
    p2 += dpp0<0xB1, 0xF>(p2);
    p3 += dpp0<0xB1, 0xF>(p3);
    p0 += dpp0<0x4E, 0xF>(p0);  // quad_perm [2,3,0,1] -> quad sums
    p1 += dpp0<0x4E, 0xF>(p1);
    p2 += dpp0<0x4E, 0xF>(p2);
    p3 += dpp0<0x4E, 0xF>(p3);

    const int c = lane & 15;
    const int sel = lane & 3;
    float v = (sel == 0) ? p0 : (sel == 1) ? p1 : (sel == 2) ? p2 : p3;
    v += dpp0<0x124, 0xF>(v);   // row_ror:4 (preserves lane&3)
    v += dpp0<0x128, 0xF>(v);   // row_ror:8 -> row total of channel sel

    const int ray = blk * 4 + (lane >> 4);
    if (c < 3) {
        rgb_out[(long)ray * 3 + c] = v;          // 12 active lanes, 1 instr
    } else if (c == 3) {
        depth_out[ray] = v;                      // 4 active lanes
    }
    if (c == 15) {
        trans_out[ray] = __builtin_amdgcn_exp2f(p);  // p = row inclusive total
    }
}

extern "C" void kernel_launch(void* const* d_in, const int* in_sizes, int n_in,
                              void* d_out, int out_size, void* d_ws, size_t ws_size,
                              hipStream_t stream) {
    const float* colors    = (const float*)d_in[0];
    const float* densities = (const float*)d_in[1];
    const float* depths    = (const float*)d_in[2];

    const int n_rays = in_sizes[1] / 64;   // densities flat count = n_rays * 64

    float* out      = (float*)d_out;
    float* rgb      = out;                              // n_rays*3
    float* depth_o  = rgb + (long)n_rays * 3;           // n_rays
    float* weights  = depth_o + n_rays;                 // n_rays*64
    float* trans    = weights + (long)n_rays * 64;      // n_rays

    const int nblk   = n_rays / 4;                      // 4 rays per wave
    const int blocks = (nblk + 3) / 4;                  // 4 waves per block
    raymarch_kernel<<<blocks, 256, 0, stream>>>(
        colors, densities, depths, rgb, depth_o, weights, trans, n_rays);
}